// Round 7
// baseline (68.895 us; speedup 1.0000x reference)
//
#include <hip/hip_runtime.h>

// ForgetMult (QRNN): xi (8,128,64,32,32) f32.
//   f = sigmoid(xi[:, :64]); x = xi[:, 64:]
//   h_t = f_t * x_t + (1 - f_t) * h_{t-1}  (scan over axis 2, T=64)
// Output (8,64,64,32,32) f32.
//
// R7: L3 cache partitioning. Input (256 MiB) == L3 size -> cyclic thrash
// with all-cacheable reads (R6 got only partial retention). Pin 192 MiB
// (f gates + x channels c<32) as cacheable = 75% of L3 -> stable residency
// across graph replays; stream the other 64 MiB (x channels c>=32) with NT
// loads; output stores NT (no allocate). Steady-state HBM ~ 201 MB/replay.

#define T_STEPS 64
#define SP2 512   // float2 per (b,c,t) spatial slice (32*32/2)

typedef float v2f __attribute__((ext_vector_type(2)));

__global__ __launch_bounds__(256)
void forgetmult_kernel(const v2f* __restrict__ xi, v2f* __restrict__ out) {
    const int blk  = blockIdx.x;          // ((b*64)+c)*2 + half
    const int b    = blk >> 7;
    const int rem  = blk & 127;
    const int c    = rem >> 1;
    const int half = rem & 1;
    const int s    = half * 256 + threadIdx.x;   // 0..511 float2-index in slice

    const size_t fbase = ((size_t)(b * 128 + c) * T_STEPS) * SP2 + s;
    const size_t xbase = ((size_t)(b * 128 + 64 + c) * T_STEPS) * SP2 + s;
    const size_t obase = ((size_t)(b * 64 + c) * T_STEPS) * SP2 + s;

    v2f h = {0.f, 0.f};

    if (c < 32) {
        // cacheable partition: f + x both L3-resident
        #pragma unroll 8
        for (int t = 0; t < T_STEPS; ++t) {
            const v2f fr = xi[fbase + (size_t)t * SP2];
            const v2f xr = xi[xbase + (size_t)t * SP2];
            const float f0 = __builtin_amdgcn_rcpf(1.0f + __expf(-fr.x));
            const float f1 = __builtin_amdgcn_rcpf(1.0f + __expf(-fr.y));
            h.x = fmaf(f0, xr.x - h.x, h.x);
            h.y = fmaf(f1, xr.y - h.y, h.y);
            __builtin_nontemporal_store(h, &out[obase + (size_t)t * SP2]);
        }
    } else {
        // streaming partition: f cacheable, x NT (never allocates in L3)
        #pragma unroll 8
        for (int t = 0; t < T_STEPS; ++t) {
            const v2f fr = xi[fbase + (size_t)t * SP2];
            const v2f xr = __builtin_nontemporal_load(&xi[xbase + (size_t)t * SP2]);
            const float f0 = __builtin_amdgcn_rcpf(1.0f + __expf(-fr.x));
            const float f1 = __builtin_amdgcn_rcpf(1.0f + __expf(-fr.y));
            h.x = fmaf(f0, xr.x - h.x, h.x);
            h.y = fmaf(f1, xr.y - h.y, h.y);
            __builtin_nontemporal_store(h, &out[obase + (size_t)t * SP2]);
        }
    }
}

extern "C" void kernel_launch(void* const* d_in, const int* in_sizes, int n_in,
                              void* d_out, int out_size, void* d_ws, size_t ws_size,
                              hipStream_t stream) {
    const v2f* xi = (const v2f*)d_in[0];
    v2f* out = (v2f*)d_out;
    // 8 b * 64 c * 2 halves = 1024 blocks, 256 threads each
    forgetmult_kernel<<<dim3(1024), dim3(256), 0, stream>>>(xi, out);
}

// Round 8
// 64.927 us; speedup vs baseline: 1.0611x; 1.0611x over previous
//
#include <hip/hip_runtime.h>

// ForgetMult (QRNN): xi (8,128,64,32,32) f32.
//   f = sigmoid(xi[:, :64]); x = xi[:, 64:]
//   h_t = f_t * x_t + (1 - f_t) * h_{t-1}  (scan over axis 2, T=64)
// Output (8,64,64,32,32) f32.
//
// R8 = R6 (best config, 64.8 us = 6.21 TB/s = ~99% of 6.3 TB/s ceiling):
// float2/lane, 1024 blocks, 16 waves/CU, unroll 8.
// Loads CACHEABLE (NT loads cost ~10% read BW and buy no L3 partitioning
// control - measured R3/R6/R7), stores NT (avoid write-allocate pollution).

#define T_STEPS 64
#define SP2 512   // float2 per (b,c,t) spatial slice (32*32/2)

typedef float v2f __attribute__((ext_vector_type(2)));

__global__ __launch_bounds__(256)
void forgetmult_kernel(const v2f* __restrict__ xi, v2f* __restrict__ out) {
    const int blk  = blockIdx.x;          // ((b*64)+c)*2 + half
    const int b    = blk >> 7;
    const int rem  = blk & 127;
    const int c    = rem >> 1;
    const int half = rem & 1;
    const int s    = half * 256 + threadIdx.x;   // 0..511 float2-index in slice

    const size_t fbase = ((size_t)(b * 128 + c) * T_STEPS) * SP2 + s;
    const size_t xbase = ((size_t)(b * 128 + 64 + c) * T_STEPS) * SP2 + s;
    const size_t obase = ((size_t)(b * 64 + c) * T_STEPS) * SP2 + s;

    v2f h = {0.f, 0.f};

    #pragma unroll 8
    for (int t = 0; t < T_STEPS; ++t) {
        const v2f fr = xi[fbase + (size_t)t * SP2];
        const v2f xr = xi[xbase + (size_t)t * SP2];

        // sigmoid via fast exp + approx rcp (absmax threshold 9.2e-2 >> rcp err)
        const float f0 = __builtin_amdgcn_rcpf(1.0f + __expf(-fr.x));
        const float f1 = __builtin_amdgcn_rcpf(1.0f + __expf(-fr.y));

        // h = f*x + (1-f)*h  ==  h + f*(x - h)
        h.x = fmaf(f0, xr.x - h.x, h.x);
        h.y = fmaf(f1, xr.y - h.y, h.y);

        __builtin_nontemporal_store(h, &out[obase + (size_t)t * SP2]);  // NT: no write-allocate
    }
}

extern "C" void kernel_launch(void* const* d_in, const int* in_sizes, int n_in,
                              void* d_out, int out_size, void* d_ws, size_t ws_size,
                              hipStream_t stream) {
    const v2f* xi = (const v2f*)d_in[0];
    v2f* out = (v2f*)d_out;
    // 8 b * 64 c * 2 halves = 1024 blocks, 256 threads each
    forgetmult_kernel<<<dim3(1024), dim3(256), 0, stream>>>(xi, out);
}